// Round 21
// baseline (150.617 us; speedup 1.0000x reference)
//
#include <hip/hip_runtime.h>
#include <hip/hip_bf16.h>

// (B,N,D) = (4,4096,256) fp32 in/out.  3-launch pipeline:
//  wsplit_h:  W fp32 -> wh fp16 (2-term split).
//  proj_all:  ONE fused q/k/v projection pass per block (p-loop): X tile is
//             read from HBM once (p=1,2 hit L1/L2) — kills the 3x X re-read
//             (~192->64 MB HBM). Per-pass epilogues are the R19/R20-verified
//             ones: Q,K -> MFMA-fragment planes (Q pre-scaled log2e);
//             V -> vfrag directly via LDS transpose.
//  attn_flash15: R20's verified 93 µs body + masked-last-tile-only
//             specialization (t < nt-1 provably needs no mask: max kg =
//             128t+127 <= q0-1). Everything else byte-identical.

#define SEQ   4096
#define DIM   256
#define LOG2E 1.4426950408889634f

typedef _Float16 f16;
typedef __attribute__((ext_vector_type(8)))  f16    f16x8;
typedef __attribute__((ext_vector_type(16))) float  f32x16;

// ---------------------------------------------------------------------------
// W fp32 [256][256] -> wh fp16. blockIdx.y selects which W.
// ---------------------------------------------------------------------------
__global__ __launch_bounds__(256) void wsplit_h(
    const float* __restrict__ Wq, const float* __restrict__ Wk,
    const float* __restrict__ Wv, f16* __restrict__ whq,
    f16* __restrict__ whk, f16* __restrict__ whv)
{
    const float* W; f16* wh;
    if (blockIdx.y == 0)      { W = Wq; wh = whq; }
    else if (blockIdx.y == 1) { W = Wk; wh = whk; }
    else                      { W = Wv; wh = whv; }
    const int i = blockIdx.x * 256 + threadIdx.x;
    wh[i] = (f16)W[i];
}

// ---------------------------------------------------------------------------
// Fused q/k/v projection, one block = 64 rows, all three outputs.
// 2-term fp16 split (verified R19/20). Grid 256 (4 batches x 64 groups).
// ---------------------------------------------------------------------------
__global__ __launch_bounds__(256) void proj_all(
    const float* __restrict__ X,
    const f16* __restrict__ whq, const float* __restrict__ bq,
    const f16* __restrict__ whk, const float* __restrict__ bk,
    const f16* __restrict__ whv, const float* __restrict__ bv,
    f16* __restrict__ outq, f16* __restrict__ outk, f16* __restrict__ outv)
{
    __shared__ f16 vtile[64][264];           // V transpose tile (33.8 KB)

    const int w = threadIdx.x >> 6, lane = threadIdx.x & 63;
    const int col = lane & 31, hi = lane >> 5;
    const int m0 = blockIdx.x * 64 + (w & 1) * 32;
    const int e0 = (w >> 1) * 128;

    #pragma unroll 1
    for (int p = 0; p < 3; ++p) {
        const f16* Wh = (p == 0) ? whq : (p == 1) ? whk : whv;
        const float* bias = (p == 0) ? bq : (p == 1) ? bk : bv;

        f32x16 acc[4] = {};
        for (int s = 0; s < 16; ++s) {
            const float* xp = X + (size_t)(m0 + col) * DIM + s * 16 + 8 * hi;
            float xv[8];
            *(float4*)&xv[0] = *(const float4*)xp;
            *(float4*)&xv[4] = *(const float4*)(xp + 4);
            f16x8 xh, xl;
            #pragma unroll
            for (int i = 0; i < 8; ++i) {
                xh[i] = (f16)xv[i];
                xl[i] = (f16)(xv[i] - (float)xh[i]);
            }
            #pragma unroll
            for (int c = 0; c < 4; ++c) {
                const size_t wo = (size_t)(e0 + c * 32 + col) * DIM + s * 16 + 8 * hi;
                const f16x8 wh = *(const f16x8*)(Wh + wo);
                acc[c] = __builtin_amdgcn_mfma_f32_32x32x16_f16(xh, wh, acc[c], 0, 0, 0);
                acc[c] = __builtin_amdgcn_mfma_f32_32x32x16_f16(xl, wh, acc[c], 0, 0, 0);
            }
        }

        if (p < 2) {
            // fragment-layout epilogue (Q, K) — verified R17-R20
            const float scale = (p == 0) ? LOG2E : 1.f;
            const int bb = m0 >> 12;
            const int m0loc = m0 & 4095;
            f16* fp = (p == 0 ? outq : outk)
                      + (size_t)bb * SEQ * DIM + (size_t)(m0loc >> 5) * 8192;
            #pragma unroll
            for (int c = 0; c < 4; ++c) {
                const int e = e0 + c * 32 + col;
                const float b = bias[e];
                const int eo = (e >> 4) * 512 + ((e >> 3) & 1) * 256 + (e & 7);
                #pragma unroll
                for (int r = 0; r < 16; ++r) {
                    const int qr = (r & 3) + 8 * (r >> 2) + 4 * hi;
                    fp[eo + qr * 8] = (f16)((acc[c][r] + b) * scale);
                }
            }
        } else {
            // V epilogue: vtile then vfrag-ordered store (verified R19/20)
            #pragma unroll
            for (int c = 0; c < 4; ++c) {
                const int e = e0 + c * 32 + col;
                const float b = bias[e];
                #pragma unroll
                for (int r = 0; r < 16; ++r) {
                    const int qr = (r & 3) + 8 * (r >> 2) + 4 * hi;
                    vtile[32 * (w & 1) + qr][e] = (f16)(acc[c][r] + b);
                }
            }
            __syncthreads();
            const int bb   = blockIdx.x >> 6;          // batch
            const int kb   = (blockIdx.x & 63) >> 1;   // 128-key block
            const int half = blockIdx.x & 1;           // keys 64*half..+63
            uint4* vout = (uint4*)outv + (size_t)bb * 131072;
            const int tid = threadIdx.x;
            const int slr = tid >> 6, l = tid & 63;
            const int row = 16 * slr + 8 * (l >> 5);
            #pragma unroll
            for (int i = 0; i < 8; ++i) {              // i = db (dim block)
                f16 tmp[8];
                #pragma unroll
                for (int j = 0; j < 8; ++j)
                    tmp[j] = vtile[row + j][32 * i + (l & 31)];
                vout[(size_t)(8 * kb + i) * 512 + (4 * half + slr) * 64 + l] =
                    *(const uint4*)tmp;
            }
        }
    }
}

// ---------------------------------------------------------------------------
// attn_flash15: R20's verified body + mask-free fast path for t < nt-1.
// ---------------------------------------------------------------------------
__global__ __launch_bounds__(256, 1) void attn_flash15(
    const uint4* __restrict__ qfrag, const uint4* __restrict__ kfrag,
    const uint4* __restrict__ vfrag, float* __restrict__ out, int nb)
{
    __shared__ uint4 Pex[2][512];        // dbuf A-frags, 16 KB
    __shared__ float mlbuf[2][2][4][32]; // [buf][m|l][kq][q], 2 KB

    int qt, b;
    if (nb == 4) {
        const int lin = blockIdx.x;       // 512 blocks = 2/CU
        const int x = lin & 7;            // XCD
        b = x >> 1;                       // 2 XCDs per batch
        const int k = lin >> 3;           // slot k and k+32 share a CU
        const int f = (k < 32) ? k : (95 - k);   // f + f' = 63
        qt = 2 * f + (x & 1);             // [0,128)
    } else { qt = blockIdx.x; b = 0; }    // grid 128

    const size_t pp = (size_t)SEQ * DIM;
    const uint4* qfb = qfrag + (size_t)b * 131072;
    const uint4* kfb = kfrag + (size_t)b * 131072;
    const uint4* vfb = vfrag + (size_t)b * 131072;
    float* outb = out + b * pp;

    const int wid = threadIdx.x >> 6, lane = threadIdx.x & 63;
    const int col = lane & 31, hi = lane >> 5;
    const int kq = wid;                   // 32-key quarter / 64-col quarter
    const int q0 = qt * 32;
    const int nt = (qt + 4) >> 2;         // 128-key tiles

    // Q fragments resident, coalesced from qfrag (16 x 1KB)
    f16x8 qhf[16];
    {
        const uint4* qp = qfb + (size_t)(q0 >> 5) * 1024 + lane;
        #pragma unroll
        for (int sl = 0; sl < 16; ++sl)
            qhf[sl] = __builtin_bit_cast(f16x8, qp[sl * 64]);
    }

    float m_run = -1e28f, l_run = 0.f;
    f32x16 oacc[2] = {};                  // cols 64*kq + {col, 32+col}

    for (int t = 0; t < nt; ++t) {
        const int key0 = t << 7;
        const int pb = t & 1;
        const uint4* kp = kfb + (size_t)(4 * t + kq) * 1024 + lane;

        // ---- QK^T: own 32-key quarter (verified 2-chain form) ----
        f32x16 s1 = {}, s2 = {};
        #pragma unroll
        for (int sl = 0; sl < 16; ++sl) {
            const f16x8 kf = __builtin_bit_cast(f16x8, kp[sl * 64]);
            if (sl & 1) s2 = __builtin_amdgcn_mfma_f32_32x32x16_f16(kf, qhf[sl], s2, 0, 0, 0);
            else        s1 = __builtin_amdgcn_mfma_f32_32x32x16_f16(kf, qhf[sl], s1, 0, 0, 0);
        }

        // ---- V prefetch A-half (slices 0..3, own 64-col quarter) ----
        const uint4* vp = vfb + (size_t)(8 * t + 2 * kq) * 512 + lane;
        f16x8 vfA[2][4];
        #pragma unroll
        for (int cg = 0; cg < 2; ++cg)
            #pragma unroll
            for (int s = 0; s < 4; ++s)
                vfA[cg][s] = __builtin_bit_cast(f16x8, vp[cg * 512 + s * 64]);

        // ---- wave-local softmax; mask only on the final tile ----
        float sv[16];
        float pmax = -1e30f, tsum = 0.f;
        if (t == nt - 1) {
            #pragma unroll
            for (int r = 0; r < 16; ++r) {
                const int kg = key0 + 32 * kq + (r & 3) + 8 * (r >> 2) + 4 * hi;
                const float x = (kg <= q0 + col) ? (s1[r] + s2[r]) : -1e30f;
                sv[r] = x;
                pmax = fmaxf(pmax, x);
            }
        } else {
            #pragma unroll
            for (int r = 0; r < 16; ++r) {
                const float x = s1[r] + s2[r];
                sv[r] = x;
                pmax = fmaxf(pmax, x);
            }
        }
        pmax = fmaxf(pmax, __shfl_xor(pmax, 32));
        pmax = fmaxf(pmax, -1e28f);       // fully-masked quarter -> p = 0
        {
            float p[16];
            #pragma unroll
            for (int r = 0; r < 16; ++r) {
                p[r] = exp2f(sv[r] - pmax);
                tsum += p[r];
            }
            tsum += __shfl_xor(tsum, 32);
            // A-frag build (verified cvt_pk + shfl_xor(32))
            uint32_t Wd[8], Od[8];
            #pragma unroll
            for (int jj = 0; jj < 8; ++jj)
                Wd[jj] = __builtin_bit_cast(uint32_t,
                    __builtin_amdgcn_cvt_pkrtz(p[2 * jj], p[2 * jj + 1]));
            #pragma unroll
            for (int jj = 0; jj < 8; ++jj)
                Od[jj] = (uint32_t)__shfl_xor((int)Wd[jj], 32);
            uint4 A0, A1;
            if (hi == 0) {
                A0.x = Wd[0]; A0.y = Wd[1]; A0.z = Od[0]; A0.w = Od[1];
                A1.x = Wd[4]; A1.y = Wd[5]; A1.z = Od[4]; A1.w = Od[5];
            } else {
                A0.x = Od[2]; A0.y = Od[3]; A0.z = Wd[2]; A0.w = Wd[3];
                A1.x = Od[6]; A1.y = Od[7]; A1.z = Wd[6]; A1.w = Wd[7];
            }
            Pex[pb][((2 * kq + 0) * 2 + hi) * 32 + col] = A0;  // keys [32kq,+16)
            Pex[pb][((2 * kq + 1) * 2 + hi) * 32 + col] = A1;  // keys [32kq+16,+16)
        }
        if (lane < 32) {
            mlbuf[pb][0][kq][col] = pmax;
            mlbuf[pb][1][kq][col] = tsum;
        }

        // ---- V prefetch B-half (slices 4..7) BEFORE the barrier ----
        f16x8 vfB[2][4];
        #pragma unroll
        for (int cg = 0; cg < 2; ++cg)
            #pragma unroll
            for (int s = 0; s < 4; ++s)
                vfB[cg][s] = __builtin_bit_cast(f16x8, vp[cg * 512 + (s + 4) * 64]);

        __syncthreads();                  // the ONLY barrier per iter

        // ---- 4-way m/l merge (verified), defer-max rescale ----
        const float mw0 = mlbuf[pb][0][0][col], mw1 = mlbuf[pb][0][1][col];
        const float mw2 = mlbuf[pb][0][2][col], mw3 = mlbuf[pb][0][3][col];
        const float tw0 = mlbuf[pb][1][0][col], tw1 = mlbuf[pb][1][1][col];
        const float tw2 = mlbuf[pb][1][2][col], tw3 = mlbuf[pb][1][3][col];
        const float mt = fmaxf(fmaxf(mw0, mw1), fmaxf(mw2, mw3));
        float scale = 1.f;
        if (__any(mt > m_run + 11.5415603f)) {   // 8-nat window (log2)
            const float m_new = fmaxf(m_run, mt);
            scale = exp2f(m_run - m_new);
            m_run = m_new;
            #pragma unroll
            for (int r = 0; r < 16; ++r) {
                const int qr = (r & 3) + 8 * (r >> 2) + 4 * hi;
                const float scr = __shfl(scale, qr | (lane & 32));
                oacc[0][r] *= scr; oacc[1][r] *= scr;
            }
        }
        const float c0 = exp2f(mw0 - m_run), c1 = exp2f(mw1 - m_run);
        const float c2 = exp2f(mw2 - m_run), c3 = exp2f(mw3 - m_run);
        l_run = l_run * scale + tw0 * c0 + tw1 * c1 + tw2 * c2 + tw3 * c3;
        const f16 ch[4] = {(f16)c0, (f16)c1, (f16)c2, (f16)c3};

        // ---- PV: 8 slices x own 64-col quarter (V in regs) ----
        #pragma unroll
        for (int s4 = 0; s4 < 4; ++s4) {
            f16x8 af = __builtin_bit_cast(f16x8, Pex[pb][(s4 * 2 + hi) * 32 + col]);
            af = af * ch[s4 >> 1];
            oacc[0] = __builtin_amdgcn_mfma_f32_32x32x16_f16(af, vfA[0][s4], oacc[0], 0, 0, 0);
            oacc[1] = __builtin_amdgcn_mfma_f32_32x32x16_f16(af, vfA[1][s4], oacc[1], 0, 0, 0);
        }
        #pragma unroll
        for (int s4 = 0; s4 < 4; ++s4) {
            f16x8 af = __builtin_bit_cast(f16x8, Pex[pb][((s4 + 4) * 2 + hi) * 32 + col]);
            af = af * ch[2 + (s4 >> 1)];
            oacc[0] = __builtin_amdgcn_mfma_f32_32x32x16_f16(af, vfB[0][s4], oacc[0], 0, 0, 0);
            oacc[1] = __builtin_amdgcn_mfma_f32_32x32x16_f16(af, vfB[1][s4], oacc[1], 0, 0, 0);
        }
        // dbuf: next iter writes Pex[pb^1]/mlbuf[pb^1]; laggard's reads of
        // Pex[pb] are safe; barrier(t+1) orders reuse of Pex[pb] at t+2.
    }

    // ---- epilogue: divide by l, store fp32 ----
    const float linv = 1.f / l_run;
    #pragma unroll
    for (int r = 0; r < 16; ++r) {
        const int qr = (r & 3) + 8 * (r >> 2) + 4 * hi;
        const float lr = __shfl(linv, qr | (lane & 32));
        const int n = q0 + qr;
        outb[(size_t)n * DIM + 64 * kq + col]      = oacc[0][r] * lr;
        outb[(size_t)n * DIM + 64 * kq + 32 + col] = oacc[1][r] * lr;
    }
}

// ---------------------------------------------------------------------------
extern "C" void kernel_launch(void* const* d_in, const int* in_sizes, int n_in,
                              void* d_out, int out_size, void* d_ws, size_t ws_size,
                              hipStream_t stream) {
    const float* x  = (const float*)d_in[0];
    const float* Wq = (const float*)d_in[1];
    const float* bq = (const float*)d_in[2];
    const float* Wk = (const float*)d_in[3];
    const float* bk = (const float*)d_in[4];
    const float* Wv = (const float*)d_in[5];
    const float* bv = (const float*)d_in[6];
    float* out = (float*)d_out;

    const size_t PP = (size_t)SEQ * DIM;            // 1M elems per batch plane
    const size_t FULL = 4 * PP;                     // 4M elems (8 MB fp16)
    const size_t WSZ = (size_t)DIM * DIM;           // 64K elems per W plane

    if (ws_size >= FULL * 2 * 5) {                  // known-true threshold
        f16* qfr = (f16*)d_ws;                      // Q fragment plane (8 MB)
        f16* kfr = qfr + FULL;                      // K fragment plane (8 MB)
        f16* vfr = kfr + FULL;                      // V fragment plane (8 MB)
        f16* whq = vfr + FULL;                      // 3 x 64K fp16 = 384 KB
        f16* whk = whq + WSZ;
        f16* whv = whk + WSZ;

        wsplit_h<<<dim3(256, 3), 256, 0, stream>>>(Wq, Wk, Wv, whq, whk, whv);
        proj_all<<<dim3(256), 256, 0, stream>>>(
            x, whq, bq, whk, bk, whv, bv, qfr, kfr, vfr);
        attn_flash15<<<dim3(512), 256, 0, stream>>>(
            (const uint4*)qfr, (const uint4*)kfr, (const uint4*)vfr, out, 4);
    } else {
        // per-batch fallback
        f16* qfr = (f16*)d_ws;
        f16* kfr = qfr + PP;
        f16* vfr = kfr + PP;
        f16* whq = vfr + PP;
        f16* whk = whq + WSZ;
        f16* whv = whk + WSZ;

        wsplit_h<<<dim3(256, 3), 256, 0, stream>>>(Wq, Wk, Wv, whq, whk, whv);
        for (int b = 0; b < 4; ++b) {
            const float* xb = x + b * PP;
            proj_all<<<dim3(64), 256, 0, stream>>>(
                xb, whq, bq, whk, bk, whv, bv, qfr, kfr, vfr);
            attn_flash15<<<dim3(128), 256, 0, stream>>>(
                (const uint4*)qfr, (const uint4*)kfr, (const uint4*)vfr, out + b * PP, 1);
        }
    }
}

// Round 22
// 126.590 us; speedup vs baseline: 1.1898x; 1.1898x over previous
//
#include <hip/hip_runtime.h>
#include <hip/hip_bf16.h>

// (B,N,D) = (4,4096,256) fp32 in/out.  3-launch pipeline — VERIFIED BEST
// (R20: 126.2 µs total, attn 93 µs, absmax 0.047):
//  wsplit_h: W fp32 -> wh fp16.
//  proj3:    fused q/k/v projection, 2-term fp16 split, grid.y=3 (768 blocks
//            = 3/CU; R21's fused p-loop dropped to 1 block/CU and lost the
//            X-traffic win to latency). Q,K -> MFMA-fragment planes;
//            V -> vfrag directly. Q pre-scaled log2e.
//  attn_flash14: verified attention body. NO setprio (R19: −23 µs),
//            NO K-prefetch (R16: neutral), NO chain-split (R17: −16 µs),
//            NO split-K (R18: −46 µs), NO mask-specialization (R21: −20 µs —
//            body duplication disrupted the compiler's schedule).
//            512 blocks x 256 thr, K/V/Q from fragment-ordered global,
//            LDS = dbuf Pex + mlbuf, 1 barrier/iter, co-residency pairing.

#define SEQ   4096
#define DIM   256
#define LOG2E 1.4426950408889634f

typedef _Float16 f16;
typedef __attribute__((ext_vector_type(8)))  f16    f16x8;
typedef __attribute__((ext_vector_type(16))) float  f32x16;

// ---------------------------------------------------------------------------
// W fp32 [256][256] -> wh fp16. blockIdx.y selects which W.
// ---------------------------------------------------------------------------
__global__ __launch_bounds__(256) void wsplit_h(
    const float* __restrict__ Wq, const float* __restrict__ Wk,
    const float* __restrict__ Wv, f16* __restrict__ whq,
    f16* __restrict__ whk, f16* __restrict__ whv)
{
    const float* W; f16* wh;
    if (blockIdx.y == 0)      { W = Wq; wh = whq; }
    else if (blockIdx.y == 1) { W = Wk; wh = whk; }
    else                      { W = Wv; wh = whv; }
    const int i = blockIdx.x * 256 + threadIdx.x;
    wh[i] = (f16)W[i];
}

// ---------------------------------------------------------------------------
// Fused projection, 2-term (verified R19/R20). blockIdx.y: 0=Q (frag, log2e),
// 1=K (frag), 2=V (vfrag via LDS transpose).
// ---------------------------------------------------------------------------
__global__ __launch_bounds__(256) void proj3(
    const float* __restrict__ X,
    const f16* __restrict__ Whq, const float* __restrict__ bq,
    const f16* __restrict__ Whk, const float* __restrict__ bk,
    const f16* __restrict__ Whv, const float* __restrict__ bv,
    f16* __restrict__ outq, f16* __restrict__ outk, f16* __restrict__ outv)
{
    __shared__ f16 vtile[64][264];           // V transpose tile (33.8 KB)

    const f16* Wh; const float* bias; float scale;
    if (blockIdx.y == 0)      { Wh = Whq; bias = bq; scale = LOG2E; }
    else if (blockIdx.y == 1) { Wh = Whk; bias = bk; scale = 1.f; }
    else                      { Wh = Whv; bias = bv; scale = 1.f; }

    const int w = threadIdx.x >> 6, lane = threadIdx.x & 63;
    const int col = lane & 31, hi = lane >> 5;
    const int m0 = blockIdx.x * 64 + (w & 1) * 32;
    const int e0 = (w >> 1) * 128;

    f32x16 acc[4] = {};
    for (int s = 0; s < 16; ++s) {
        const float* xp = X + (size_t)(m0 + col) * DIM + s * 16 + 8 * hi;
        float xv[8];
        *(float4*)&xv[0] = *(const float4*)xp;
        *(float4*)&xv[4] = *(const float4*)(xp + 4);
        f16x8 xh, xl;
        #pragma unroll
        for (int i = 0; i < 8; ++i) {
            xh[i] = (f16)xv[i];
            xl[i] = (f16)(xv[i] - (float)xh[i]);
        }
        #pragma unroll
        for (int c = 0; c < 4; ++c) {
            const size_t wo = (size_t)(e0 + c * 32 + col) * DIM + s * 16 + 8 * hi;
            const f16x8 wh = *(const f16x8*)(Wh + wo);
            acc[c] = __builtin_amdgcn_mfma_f32_32x32x16_f16(xh, wh, acc[c], 0, 0, 0);
            acc[c] = __builtin_amdgcn_mfma_f32_32x32x16_f16(xl, wh, acc[c], 0, 0, 0);
        }
    }

    if (blockIdx.y < 2) {
        // fragment-layout epilogue (Q, K) — verified R17-R20
        const int bb = m0 >> 12;
        const int m0loc = m0 & 4095;
        f16* fp = (blockIdx.y == 0 ? outq : outk)
                  + (size_t)bb * SEQ * DIM + (size_t)(m0loc >> 5) * 8192;
        #pragma unroll
        for (int c = 0; c < 4; ++c) {
            const int e = e0 + c * 32 + col;
            const float b = bias[e];
            const int eo = (e >> 4) * 512 + ((e >> 3) & 1) * 256 + (e & 7);
            #pragma unroll
            for (int r = 0; r < 16; ++r) {
                const int qr = (r & 3) + 8 * (r >> 2) + 4 * hi;
                fp[eo + qr * 8] = (f16)((acc[c][r] + b) * scale);
            }
        }
    } else {
        // V epilogue: vtile[keyrel][dim] then vfrag-ordered store (verified R19/20)
        #pragma unroll
        for (int c = 0; c < 4; ++c) {
            const int e = e0 + c * 32 + col;
            const float b = bias[e];
            #pragma unroll
            for (int r = 0; r < 16; ++r) {
                const int qr = (r & 3) + 8 * (r >> 2) + 4 * hi;
                vtile[32 * (w & 1) + qr][e] = (f16)(acc[c][r] + b);
            }
        }
        __syncthreads();
        const int bb   = blockIdx.x >> 6;          // batch (64 blocks/batch)
        const int kb   = (blockIdx.x & 63) >> 1;   // 128-key block
        const int half = blockIdx.x & 1;           // keys 64*half..+63
        uint4* vout = (uint4*)outv + (size_t)bb * 131072;
        const int tid = threadIdx.x;
        const int slr = tid >> 6, l = tid & 63;
        const int row = 16 * slr + 8 * (l >> 5);
        #pragma unroll
        for (int i = 0; i < 8; ++i) {              // i = db (dim block)
            f16 tmp[8];
            #pragma unroll
            for (int j = 0; j < 8; ++j)
                tmp[j] = vtile[row + j][32 * i + (l & 31)];
            vout[(size_t)(8 * kb + i) * 512 + (4 * half + slr) * 64 + l] =
                *(const uint4*)tmp;
        }
    }
}

// ---------------------------------------------------------------------------
// attn_flash14: verified R15/R16/R20 attention body (no setprio, no prefetch).
// ---------------------------------------------------------------------------
__global__ __launch_bounds__(256, 1) void attn_flash14(
    const uint4* __restrict__ qfrag, const uint4* __restrict__ kfrag,
    const uint4* __restrict__ vfrag, float* __restrict__ out, int nb)
{
    __shared__ uint4 Pex[2][512];        // dbuf A-frags, 16 KB
    __shared__ float mlbuf[2][2][4][32]; // [buf][m|l][kq][q], 2 KB

    int qt, b;
    if (nb == 4) {
        const int lin = blockIdx.x;       // 512 blocks = 2/CU
        const int x = lin & 7;            // XCD
        b = x >> 1;                       // 2 XCDs per batch
        const int k = lin >> 3;           // slot k and k+32 share a CU
        const int f = (k < 32) ? k : (95 - k);   // f + f' = 63
        qt = 2 * f + (x & 1);             // [0,128)
    } else { qt = blockIdx.x; b = 0; }    // grid 128

    const size_t pp = (size_t)SEQ * DIM;
    const uint4* qfb = qfrag + (size_t)b * 131072;
    const uint4* kfb = kfrag + (size_t)b * 131072;
    const uint4* vfb = vfrag + (size_t)b * 131072;
    float* outb = out + b * pp;

    const int wid = threadIdx.x >> 6, lane = threadIdx.x & 63;
    const int col = lane & 31, hi = lane >> 5;
    const int kq = wid;                   // 32-key quarter / 64-col quarter
    const int q0 = qt * 32;
    const int nt = (qt + 4) >> 2;         // 128-key tiles

    // Q fragments resident, coalesced from qfrag (16 x 1KB)
    f16x8 qhf[16];
    {
        const uint4* qp = qfb + (size_t)(q0 >> 5) * 1024 + lane;
        #pragma unroll
        for (int sl = 0; sl < 16; ++sl)
            qhf[sl] = __builtin_bit_cast(f16x8, qp[sl * 64]);
    }

    float m_run = -1e28f, l_run = 0.f;
    f32x16 oacc[2] = {};                  // cols 64*kq + {col, 32+col}

    for (int t = 0; t < nt; ++t) {
        const int key0 = t << 7;
        const int pb = t & 1;
        const uint4* kp = kfb + (size_t)(4 * t + kq) * 1024 + lane;

        // ---- QK^T: own 32-key quarter (verified 2-chain form) ----
        f32x16 s1 = {}, s2 = {};
        #pragma unroll
        for (int sl = 0; sl < 16; ++sl) {
            const f16x8 kf = __builtin_bit_cast(f16x8, kp[sl * 64]);
            if (sl & 1) s2 = __builtin_amdgcn_mfma_f32_32x32x16_f16(kf, qhf[sl], s2, 0, 0, 0);
            else        s1 = __builtin_amdgcn_mfma_f32_32x32x16_f16(kf, qhf[sl], s1, 0, 0, 0);
        }

        // ---- V prefetch A-half (slices 0..3, own 64-col quarter) ----
        const uint4* vp = vfb + (size_t)(8 * t + 2 * kq) * 512 + lane;
        f16x8 vfA[2][4];
        #pragma unroll
        for (int cg = 0; cg < 2; ++cg)
            #pragma unroll
            for (int s = 0; s < 4; ++s)
                vfA[cg][s] = __builtin_bit_cast(f16x8, vp[cg * 512 + s * 64]);

        // ---- mask + wave-local softmax (verified R10-R16 verbatim) ----
        float sv[16];
        float pmax = -1e30f, tsum = 0.f;
        #pragma unroll
        for (int r = 0; r < 16; ++r) {
            const int kg = key0 + 32 * kq + (r & 3) + 8 * (r >> 2) + 4 * hi;
            const float x = (kg <= q0 + col) ? (s1[r] + s2[r]) : -1e30f;
            sv[r] = x;
            pmax = fmaxf(pmax, x);
        }
        pmax = fmaxf(pmax, __shfl_xor(pmax, 32));
        pmax = fmaxf(pmax, -1e28f);       // fully-masked quarter -> p = 0
        {
            float p[16];
            #pragma unroll
            for (int r = 0; r < 16; ++r) {
                p[r] = exp2f(sv[r] - pmax);
                tsum += p[r];
            }
            tsum += __shfl_xor(tsum, 32);
            // A-frag build (verified cvt_pk + shfl_xor(32))
            uint32_t Wd[8], Od[8];
            #pragma unroll
            for (int jj = 0; jj < 8; ++jj)
                Wd[jj] = __builtin_bit_cast(uint32_t,
                    __builtin_amdgcn_cvt_pkrtz(p[2 * jj], p[2 * jj + 1]));
            #pragma unroll
            for (int jj = 0; jj < 8; ++jj)
                Od[jj] = (uint32_t)__shfl_xor((int)Wd[jj], 32);
            uint4 A0, A1;
            if (hi == 0) {
                A0.x = Wd[0]; A0.y = Wd[1]; A0.z = Od[0]; A0.w = Od[1];
                A1.x = Wd[4]; A1.y = Wd[5]; A1.z = Od[4]; A1.w = Od[5];
            } else {
                A0.x = Od[2]; A0.y = Od[3]; A0.z = Wd[2]; A0.w = Wd[3];
                A1.x = Od[6]; A1.y = Od[7]; A1.z = Wd[6]; A1.w = Wd[7];
            }
            Pex[pb][((2 * kq + 0) * 2 + hi) * 32 + col] = A0;  // keys [32kq,+16)
            Pex[pb][((2 * kq + 1) * 2 + hi) * 32 + col] = A1;  // keys [32kq+16,+16)
        }
        if (lane < 32) {
            mlbuf[pb][0][kq][col] = pmax;
            mlbuf[pb][1][kq][col] = tsum;
        }

        // ---- V prefetch B-half (slices 4..7) BEFORE the barrier ----
        f16x8 vfB[2][4];
        #pragma unroll
        for (int cg = 0; cg < 2; ++cg)
            #pragma unroll
            for (int s = 0; s < 4; ++s)
                vfB[cg][s] = __builtin_bit_cast(f16x8, vp[cg * 512 + (s + 4) * 64]);

        __syncthreads();                  // the ONLY barrier per iter

        // ---- 4-way m/l merge (verified), defer-max rescale ----
        const float mw0 = mlbuf[pb][0][0][col], mw1 = mlbuf[pb][0][1][col];
        const float mw2 = mlbuf[pb][0][2][col], mw3 = mlbuf[pb][0][3][col];
        const float tw0 = mlbuf[pb][1][0][col], tw1 = mlbuf[pb][1][1][col];
        const float tw2 = mlbuf[pb][1][2][col], tw3 = mlbuf[pb][1][3][col];
        const float mt = fmaxf(fmaxf(mw0, mw1), fmaxf(mw2, mw3));
        float scale = 1.f;
        if (__any(mt > m_run + 11.5415603f)) {   // 8-nat window (log2)
            const float m_new = fmaxf(m_run, mt);
            scale = exp2f(m_run - m_new);
            m_run = m_new;
            #pragma unroll
            for (int r = 0; r < 16; ++r) {
                const int qr = (r & 3) + 8 * (r >> 2) + 4 * hi;
                const float scr = __shfl(scale, qr | (lane & 32));
                oacc[0][r] *= scr; oacc[1][r] *= scr;
            }
        }
        const float c0 = exp2f(mw0 - m_run), c1 = exp2f(mw1 - m_run);
        const float c2 = exp2f(mw2 - m_run), c3 = exp2f(mw3 - m_run);
        l_run = l_run * scale + tw0 * c0 + tw1 * c1 + tw2 * c2 + tw3 * c3;
        const f16 ch[4] = {(f16)c0, (f16)c1, (f16)c2, (f16)c3};

        // ---- PV: 8 slices x own 64-col quarter (V in regs) ----
        #pragma unroll
        for (int s4 = 0; s4 < 4; ++s4) {
            f16x8 af = __builtin_bit_cast(f16x8, Pex[pb][(s4 * 2 + hi) * 32 + col]);
            af = af * ch[s4 >> 1];
            oacc[0] = __builtin_amdgcn_mfma_f32_32x32x16_f16(af, vfA[0][s4], oacc[0], 0, 0, 0);
            oacc[1] = __builtin_amdgcn_mfma_f32_32x32x16_f16(af, vfA[1][s4], oacc[1], 0, 0, 0);
        }
        #pragma unroll
        for (int s4 = 0; s4 < 4; ++s4) {
            f16x8 af = __builtin_bit_cast(f16x8, Pex[pb][((s4 + 4) * 2 + hi) * 32 + col]);
            af = af * ch[2 + (s4 >> 1)];
            oacc[0] = __builtin_amdgcn_mfma_f32_32x32x16_f16(af, vfB[0][s4], oacc[0], 0, 0, 0);
            oacc[1] = __builtin_amdgcn_mfma_f32_32x32x16_f16(af, vfB[1][s4], oacc[1], 0, 0, 0);
        }
        // dbuf: next iter writes Pex[pb^1]/mlbuf[pb^1]; laggard's reads of
        // Pex[pb] are safe; barrier(t+1) orders reuse of Pex[pb] at t+2.
    }

    // ---- epilogue: divide by l, store fp32 ----
    const float linv = 1.f / l_run;
    #pragma unroll
    for (int r = 0; r < 16; ++r) {
        const int qr = (r & 3) + 8 * (r >> 2) + 4 * hi;
        const float lr = __shfl(linv, qr | (lane & 32));
        const int n = q0 + qr;
        outb[(size_t)n * DIM + 64 * kq + col]      = oacc[0][r] * lr;
        outb[(size_t)n * DIM + 64 * kq + 32 + col] = oacc[1][r] * lr;
    }
}

// ---------------------------------------------------------------------------
extern "C" void kernel_launch(void* const* d_in, const int* in_sizes, int n_in,
                              void* d_out, int out_size, void* d_ws, size_t ws_size,
                              hipStream_t stream) {
    const float* x  = (const float*)d_in[0];
    const float* Wq = (const float*)d_in[1];
    const float* bq = (const float*)d_in[2];
    const float* Wk = (const float*)d_in[3];
    const float* bk = (const float*)d_in[4];
    const float* Wv = (const float*)d_in[5];
    const float* bv = (const float*)d_in[6];
    float* out = (float*)d_out;

    const size_t PP = (size_t)SEQ * DIM;            // 1M elems per batch plane
    const size_t FULL = 4 * PP;                     // 4M elems (8 MB fp16)
    const size_t WSZ = (size_t)DIM * DIM;           // 64K elems per W plane

    if (ws_size >= FULL * 2 * 5) {                  // known-true threshold
        f16* qfr = (f16*)d_ws;                      // Q fragment plane (8 MB)
        f16* kfr = qfr + FULL;                      // K fragment plane (8 MB)
        f16* vfr = kfr + FULL;                      // V fragment plane (8 MB)
        f16* whq = vfr + FULL;                      // 3 x 64K fp16 = 384 KB
        f16* whk = whq + WSZ;
        f16* whv = whk + WSZ;

        wsplit_h<<<dim3(256, 3), 256, 0, stream>>>(Wq, Wk, Wv, whq, whk, whv);
        proj3<<<dim3(256, 3), 256, 0, stream>>>(
            x, whq, bq, whk, bk, whv, bv, qfr, kfr, vfr);
        attn_flash14<<<dim3(512), 256, 0, stream>>>(
            (const uint4*)qfr, (const uint4*)kfr, (const uint4*)vfr, out, 4);
    } else {
        // per-batch fallback
        f16* qfr = (f16*)d_ws;
        f16* kfr = qfr + PP;
        f16* vfr = kfr + PP;
        f16* whq = vfr + PP;
        f16* whk = whq + WSZ;
        f16* whv = whk + WSZ;

        wsplit_h<<<dim3(256, 3), 256, 0, stream>>>(Wq, Wk, Wv, whq, whk, whv);
        for (int b = 0; b < 4; ++b) {
            const float* xb = x + b * PP;
            proj3<<<dim3(64, 3), 256, 0, stream>>>(
                xb, whq, bq, whk, bk, whv, bv, qfr, kfr, vfr);
            attn_flash14<<<dim3(128), 256, 0, stream>>>(
                (const uint4*)qfr, (const uint4*)kfr, (const uint4*)vfr, out + b * PP, 1);
        }
    }
}

// Round 23
// 126.410 us; speedup vs baseline: 1.1915x; 1.0014x over previous
//
#include <hip/hip_runtime.h>
#include <hip/hip_bf16.h>

// (B,N,D) = (4,4096,256) fp32 in/out.  3-launch pipeline:
//  wsplit_h: W fp32 -> wh fp16.                                (R22 verbatim)
//  proj3:    fused q/k/v projection, 1-TERM fp16 (xh*wh — R23 change: the
//            2-term split was 12.9 GFLOP MFMA ~ the whole pre-attn cost;
//            X-round adds ~0.01 nats score noise, inside the 0.107 budget).
//            Q,K -> MFMA-fragment planes; V -> vfrag directly.
//  attn_flash14: verified 93 µs body (R20/R22), byte-identical. NO setprio,
//            NO K-prefetch, NO chain-split, NO split-K, NO mask-special.

#define SEQ   4096
#define DIM   256
#define LOG2E 1.4426950408889634f

typedef _Float16 f16;
typedef __attribute__((ext_vector_type(8)))  f16    f16x8;
typedef __attribute__((ext_vector_type(16))) float  f32x16;

// ---------------------------------------------------------------------------
// W fp32 [256][256] -> wh fp16. blockIdx.y selects which W.
// ---------------------------------------------------------------------------
__global__ __launch_bounds__(256) void wsplit_h(
    const float* __restrict__ Wq, const float* __restrict__ Wk,
    const float* __restrict__ Wv, f16* __restrict__ whq,
    f16* __restrict__ whk, f16* __restrict__ whv)
{
    const float* W; f16* wh;
    if (blockIdx.y == 0)      { W = Wq; wh = whq; }
    else if (blockIdx.y == 1) { W = Wk; wh = whk; }
    else                      { W = Wv; wh = whv; }
    const int i = blockIdx.x * 256 + threadIdx.x;
    wh[i] = (f16)W[i];
}

// ---------------------------------------------------------------------------
// Fused projection, 1-term fp16. blockIdx.y: 0=Q (frag, log2e), 1=K (frag),
// 2=V (vfrag via LDS transpose). Epilogues verified R17-R22.
// ---------------------------------------------------------------------------
__global__ __launch_bounds__(256) void proj3(
    const float* __restrict__ X,
    const f16* __restrict__ Whq, const float* __restrict__ bq,
    const f16* __restrict__ Whk, const float* __restrict__ bk,
    const f16* __restrict__ Whv, const float* __restrict__ bv,
    f16* __restrict__ outq, f16* __restrict__ outk, f16* __restrict__ outv)
{
    __shared__ f16 vtile[64][264];           // V transpose tile (33.8 KB)

    const f16* Wh; const float* bias; float scale;
    if (blockIdx.y == 0)      { Wh = Whq; bias = bq; scale = LOG2E; }
    else if (blockIdx.y == 1) { Wh = Whk; bias = bk; scale = 1.f; }
    else                      { Wh = Whv; bias = bv; scale = 1.f; }

    const int w = threadIdx.x >> 6, lane = threadIdx.x & 63;
    const int col = lane & 31, hi = lane >> 5;
    const int m0 = blockIdx.x * 64 + (w & 1) * 32;
    const int e0 = (w >> 1) * 128;

    f32x16 acc[4] = {};
    for (int s = 0; s < 16; ++s) {
        const float* xp = X + (size_t)(m0 + col) * DIM + s * 16 + 8 * hi;
        float xv[8];
        *(float4*)&xv[0] = *(const float4*)xp;
        *(float4*)&xv[4] = *(const float4*)(xp + 4);
        f16x8 xh;
        #pragma unroll
        for (int i = 0; i < 8; ++i) xh[i] = (f16)xv[i];
        #pragma unroll
        for (int c = 0; c < 4; ++c) {
            const size_t wo = (size_t)(e0 + c * 32 + col) * DIM + s * 16 + 8 * hi;
            const f16x8 wh = *(const f16x8*)(Wh + wo);
            acc[c] = __builtin_amdgcn_mfma_f32_32x32x16_f16(xh, wh, acc[c], 0, 0, 0);
        }
    }

    if (blockIdx.y < 2) {
        // fragment-layout epilogue (Q, K) — verified R17-R22
        const int bb = m0 >> 12;
        const int m0loc = m0 & 4095;
        f16* fp = (blockIdx.y == 0 ? outq : outk)
                  + (size_t)bb * SEQ * DIM + (size_t)(m0loc >> 5) * 8192;
        #pragma unroll
        for (int c = 0; c < 4; ++c) {
            const int e = e0 + c * 32 + col;
            const float b = bias[e];
            const int eo = (e >> 4) * 512 + ((e >> 3) & 1) * 256 + (e & 7);
            #pragma unroll
            for (int r = 0; r < 16; ++r) {
                const int qr = (r & 3) + 8 * (r >> 2) + 4 * hi;
                fp[eo + qr * 8] = (f16)((acc[c][r] + b) * scale);
            }
        }
    } else {
        // V epilogue: vtile[keyrel][dim] then vfrag-ordered store (verified)
        #pragma unroll
        for (int c = 0; c < 4; ++c) {
            const int e = e0 + c * 32 + col;
            const float b = bias[e];
            #pragma unroll
            for (int r = 0; r < 16; ++r) {
                const int qr = (r & 3) + 8 * (r >> 2) + 4 * hi;
                vtile[32 * (w & 1) + qr][e] = (f16)(acc[c][r] + b);
            }
        }
        __syncthreads();
        const int bb   = blockIdx.x >> 6;          // batch (64 blocks/batch)
        const int kb   = (blockIdx.x & 63) >> 1;   // 128-key block
        const int half = blockIdx.x & 1;           // keys 64*half..+63
        uint4* vout = (uint4*)outv + (size_t)bb * 131072;
        const int tid = threadIdx.x;
        const int slr = tid >> 6, l = tid & 63;
        const int row = 16 * slr + 8 * (l >> 5);
        #pragma unroll
        for (int i = 0; i < 8; ++i) {              // i = db (dim block)
            f16 tmp[8];
            #pragma unroll
            for (int j = 0; j < 8; ++j)
                tmp[j] = vtile[row + j][32 * i + (l & 31)];
            vout[(size_t)(8 * kb + i) * 512 + (4 * half + slr) * 64 + l] =
                *(const uint4*)tmp;
        }
    }
}

// ---------------------------------------------------------------------------
// attn_flash14: verified R15/R16/R20/R22 attention body (byte-identical).
// ---------------------------------------------------------------------------
__global__ __launch_bounds__(256, 1) void attn_flash14(
    const uint4* __restrict__ qfrag, const uint4* __restrict__ kfrag,
    const uint4* __restrict__ vfrag, float* __restrict__ out, int nb)
{
    __shared__ uint4 Pex[2][512];        // dbuf A-frags, 16 KB
    __shared__ float mlbuf[2][2][4][32]; // [buf][m|l][kq][q], 2 KB

    int qt, b;
    if (nb == 4) {
        const int lin = blockIdx.x;       // 512 blocks = 2/CU
        const int x = lin & 7;            // XCD
        b = x >> 1;                       // 2 XCDs per batch
        const int k = lin >> 3;           // slot k and k+32 share a CU
        const int f = (k < 32) ? k : (95 - k);   // f + f' = 63
        qt = 2 * f + (x & 1);             // [0,128)
    } else { qt = blockIdx.x; b = 0; }    // grid 128

    const size_t pp = (size_t)SEQ * DIM;
    const uint4* qfb = qfrag + (size_t)b * 131072;
    const uint4* kfb = kfrag + (size_t)b * 131072;
    const uint4* vfb = vfrag + (size_t)b * 131072;
    float* outb = out + b * pp;

    const int wid = threadIdx.x >> 6, lane = threadIdx.x & 63;
    const int col = lane & 31, hi = lane >> 5;
    const int kq = wid;                   // 32-key quarter / 64-col quarter
    const int q0 = qt * 32;
    const int nt = (qt + 4) >> 2;         // 128-key tiles

    // Q fragments resident, coalesced from qfrag (16 x 1KB)
    f16x8 qhf[16];
    {
        const uint4* qp = qfb + (size_t)(q0 >> 5) * 1024 + lane;
        #pragma unroll
        for (int sl = 0; sl < 16; ++sl)
            qhf[sl] = __builtin_bit_cast(f16x8, qp[sl * 64]);
    }

    float m_run = -1e28f, l_run = 0.f;
    f32x16 oacc[2] = {};                  // cols 64*kq + {col, 32+col}

    for (int t = 0; t < nt; ++t) {
        const int key0 = t << 7;
        const int pb = t & 1;
        const uint4* kp = kfb + (size_t)(4 * t + kq) * 1024 + lane;

        // ---- QK^T: own 32-key quarter (verified 2-chain form) ----
        f32x16 s1 = {}, s2 = {};
        #pragma unroll
        for (int sl = 0; sl < 16; ++sl) {
            const f16x8 kf = __builtin_bit_cast(f16x8, kp[sl * 64]);
            if (sl & 1) s2 = __builtin_amdgcn_mfma_f32_32x32x16_f16(kf, qhf[sl], s2, 0, 0, 0);
            else        s1 = __builtin_amdgcn_mfma_f32_32x32x16_f16(kf, qhf[sl], s1, 0, 0, 0);
        }

        // ---- V prefetch A-half (slices 0..3, own 64-col quarter) ----
        const uint4* vp = vfb + (size_t)(8 * t + 2 * kq) * 512 + lane;
        f16x8 vfA[2][4];
        #pragma unroll
        for (int cg = 0; cg < 2; ++cg)
            #pragma unroll
            for (int s = 0; s < 4; ++s)
                vfA[cg][s] = __builtin_bit_cast(f16x8, vp[cg * 512 + s * 64]);

        // ---- mask + wave-local softmax (verified R10-R16 verbatim) ----
        float sv[16];
        float pmax = -1e30f, tsum = 0.f;
        #pragma unroll
        for (int r = 0; r < 16; ++r) {
            const int kg = key0 + 32 * kq + (r & 3) + 8 * (r >> 2) + 4 * hi;
            const float x = (kg <= q0 + col) ? (s1[r] + s2[r]) : -1e30f;
            sv[r] = x;
            pmax = fmaxf(pmax, x);
        }
        pmax = fmaxf(pmax, __shfl_xor(pmax, 32));
        pmax = fmaxf(pmax, -1e28f);       // fully-masked quarter -> p = 0
        {
            float p[16];
            #pragma unroll
            for (int r = 0; r < 16; ++r) {
                p[r] = exp2f(sv[r] - pmax);
                tsum += p[r];
            }
            tsum += __shfl_xor(tsum, 32);
            // A-frag build (verified cvt_pk + shfl_xor(32))
            uint32_t Wd[8], Od[8];
            #pragma unroll
            for (int jj = 0; jj < 8; ++jj)
                Wd[jj] = __builtin_bit_cast(uint32_t,
                    __builtin_amdgcn_cvt_pkrtz(p[2 * jj], p[2 * jj + 1]));
            #pragma unroll
            for (int jj = 0; jj < 8; ++jj)
                Od[jj] = (uint32_t)__shfl_xor((int)Wd[jj], 32);
            uint4 A0, A1;
            if (hi == 0) {
                A0.x = Wd[0]; A0.y = Wd[1]; A0.z = Od[0]; A0.w = Od[1];
                A1.x = Wd[4]; A1.y = Wd[5]; A1.z = Od[4]; A1.w = Od[5];
            } else {
                A0.x = Od[2]; A0.y = Od[3]; A0.z = Wd[2]; A0.w = Wd[3];
                A1.x = Od[6]; A1.y = Od[7]; A1.z = Wd[6]; A1.w = Wd[7];
            }
            Pex[pb][((2 * kq + 0) * 2 + hi) * 32 + col] = A0;  // keys [32kq,+16)
            Pex[pb][((2 * kq + 1) * 2 + hi) * 32 + col] = A1;  // keys [32kq+16,+16)
        }
        if (lane < 32) {
            mlbuf[pb][0][kq][col] = pmax;
            mlbuf[pb][1][kq][col] = tsum;
        }

        // ---- V prefetch B-half (slices 4..7) BEFORE the barrier ----
        f16x8 vfB[2][4];
        #pragma unroll
        for (int cg = 0; cg < 2; ++cg)
            #pragma unroll
            for (int s = 0; s < 4; ++s)
                vfB[cg][s] = __builtin_bit_cast(f16x8, vp[cg * 512 + (s + 4) * 64]);

        __syncthreads();                  // the ONLY barrier per iter

        // ---- 4-way m/l merge (verified), defer-max rescale ----
        const float mw0 = mlbuf[pb][0][0][col], mw1 = mlbuf[pb][0][1][col];
        const float mw2 = mlbuf[pb][0][2][col], mw3 = mlbuf[pb][0][3][col];
        const float tw0 = mlbuf[pb][1][0][col], tw1 = mlbuf[pb][1][1][col];
        const float tw2 = mlbuf[pb][1][2][col], tw3 = mlbuf[pb][1][3][col];
        const float mt = fmaxf(fmaxf(mw0, mw1), fmaxf(mw2, mw3));
        float scale = 1.f;
        if (__any(mt > m_run + 11.5415603f)) {   // 8-nat window (log2)
            const float m_new = fmaxf(m_run, mt);
            scale = exp2f(m_run - m_new);
            m_run = m_new;
            #pragma unroll
            for (int r = 0; r < 16; ++r) {
                const int qr = (r & 3) + 8 * (r >> 2) + 4 * hi;
                const float scr = __shfl(scale, qr | (lane & 32));
                oacc[0][r] *= scr; oacc[1][r] *= scr;
            }
        }
        const float c0 = exp2f(mw0 - m_run), c1 = exp2f(mw1 - m_run);
        const float c2 = exp2f(mw2 - m_run), c3 = exp2f(mw3 - m_run);
        l_run = l_run * scale + tw0 * c0 + tw1 * c1 + tw2 * c2 + tw3 * c3;
        const f16 ch[4] = {(f16)c0, (f16)c1, (f16)c2, (f16)c3};

        // ---- PV: 8 slices x own 64-col quarter (V in regs) ----
        #pragma unroll
        for (int s4 = 0; s4 < 4; ++s4) {
            f16x8 af = __builtin_bit_cast(f16x8, Pex[pb][(s4 * 2 + hi) * 32 + col]);
            af = af * ch[s4 >> 1];
            oacc[0] = __builtin_amdgcn_mfma_f32_32x32x16_f16(af, vfA[0][s4], oacc[0], 0, 0, 0);
            oacc[1] = __builtin_amdgcn_mfma_f32_32x32x16_f16(af, vfA[1][s4], oacc[1], 0, 0, 0);
        }
        #pragma unroll
        for (int s4 = 0; s4 < 4; ++s4) {
            f16x8 af = __builtin_bit_cast(f16x8, Pex[pb][((s4 + 4) * 2 + hi) * 32 + col]);
            af = af * ch[2 + (s4 >> 1)];
            oacc[0] = __builtin_amdgcn_mfma_f32_32x32x16_f16(af, vfB[0][s4], oacc[0], 0, 0, 0);
            oacc[1] = __builtin_amdgcn_mfma_f32_32x32x16_f16(af, vfB[1][s4], oacc[1], 0, 0, 0);
        }
        // dbuf: next iter writes Pex[pb^1]/mlbuf[pb^1]; laggard's reads of
        // Pex[pb] are safe; barrier(t+1) orders reuse of Pex[pb] at t+2.
    }

    // ---- epilogue: divide by l, store fp32 ----
    const float linv = 1.f / l_run;
    #pragma unroll
    for (int r = 0; r < 16; ++r) {
        const int qr = (r & 3) + 8 * (r >> 2) + 4 * hi;
        const float lr = __shfl(linv, qr | (lane & 32));
        const int n = q0 + qr;
        outb[(size_t)n * DIM + 64 * kq + col]      = oacc[0][r] * lr;
        outb[(size_t)n * DIM + 64 * kq + 32 + col] = oacc[1][r] * lr;
    }
}

// ---------------------------------------------------------------------------
extern "C" void kernel_launch(void* const* d_in, const int* in_sizes, int n_in,
                              void* d_out, int out_size, void* d_ws, size_t ws_size,
                              hipStream_t stream) {
    const float* x  = (const float*)d_in[0];
    const float* Wq = (const float*)d_in[1];
    const float* bq = (const float*)d_in[2];
    const float* Wk = (const float*)d_in[3];
    const float* bk = (const float*)d_in[4];
    const float* Wv = (const float*)d_in[5];
    const float* bv = (const float*)d_in[6];
    float* out = (float*)d_out;

    const size_t PP = (size_t)SEQ * DIM;            // 1M elems per batch plane
    const size_t FULL = 4 * PP;                     // 4M elems (8 MB fp16)
    const size_t WSZ = (size_t)DIM * DIM;           // 64K elems per W plane

    if (ws_size >= FULL * 2 * 5) {                  // known-true threshold
        f16* qfr = (f16*)d_ws;                      // Q fragment plane (8 MB)
        f16* kfr = qfr + FULL;                      // K fragment plane (8 MB)
        f16* vfr = kfr + FULL;                      // V fragment plane (8 MB)
        f16* whq = vfr + FULL;                      // 3 x 64K fp16 = 384 KB
        f16* whk = whq + WSZ;
        f16* whv = whk + WSZ;

        wsplit_h<<<dim3(256, 3), 256, 0, stream>>>(Wq, Wk, Wv, whq, whk, whv);
        proj3<<<dim3(256, 3), 256, 0, stream>>>(
            x, whq, bq, whk, bk, whv, bv, qfr, kfr, vfr);
        attn_flash14<<<dim3(512), 256, 0, stream>>>(
            (const uint4*)qfr, (const uint4*)kfr, (const uint4*)vfr, out, 4);
    } else {
        // per-batch fallback
        f16* qfr = (f16*)d_ws;
        f16* kfr = qfr + PP;
        f16* vfr = kfr + PP;
        f16* whq = vfr + PP;
        f16* whk = whq + WSZ;
        f16* whv = whk + WSZ;

        wsplit_h<<<dim3(256, 3), 256, 0, stream>>>(Wq, Wk, Wv, whq, whk, whv);
        for (int b = 0; b < 4; ++b) {
            const float* xb = x + b * PP;
            proj3<<<dim3(64, 3), 256, 0, stream>>>(
                xb, whq, bq, whk, bk, whv, bv, qfr, kfr, vfr);
            attn_flash14<<<dim3(128), 256, 0, stream>>>(
                (const uint4*)qfr, (const uint4*)kfr, (const uint4*)vfr, out + b * PP, 1);
        }
    }
}